// Round 2
// baseline (92.837 us; speedup 1.0000x reference)
//
#include <hip/hip_runtime.h>
#include <math.h>

#define HIDDEN 2048
#define IN_F 350
#define NBLK 256
#define NTHR 1024

// ws layout (floats):
//   [0    .. 2047]  h1
//   [2048 .. 4095]  h2
//   [4096]          barrier arrive-counter (uint)
//   [4097]          barrier release flag   (uint)

__device__ __forceinline__ float sigmoidf_(float v) { return 1.0f / (1.0f + expf(-v)); }

// 350-element feature vector from x (133 keypoint pairs) into LDS.
__device__ void compute_feat(const float* __restrict__ x, float* feat) {
    __shared__ float sc[12];
    const int t = threadIdx.x;
    if (t == 0) {
        sc[0] = x[0];   sc[1] = x[1];     // src_body  = kp[0]
        sc[2] = x[106]; sc[3] = x[107];   // src_face  = kp[53]
        sc[4] = x[200]; sc[5] = x[201];   // src_left  = kp[100]
        sc[6] = x[242]; sc[7] = x[243];   // src_right = kp[121]
        float lminx = x[182], lmaxx = x[182], lminy = x[183], lmaxy = x[183];
        for (int j = 1; j < 21; ++j) {
            float vx = x[182 + 2*j], vy = x[183 + 2*j];
            lminx = fminf(lminx, vx); lmaxx = fmaxf(lmaxx, vx);
            lminy = fminf(lminy, vy); lmaxy = fmaxf(lmaxy, vy);
        }
        float wl = lmaxx - lminx, hl = lmaxy - lminy;
        float rminx = x[224], rmaxx = x[224], rminy = x[225], rmaxy = x[225];
        for (int j = 1; j < 21; ++j) {
            float vx = x[224 + 2*j], vy = x[225 + 2*j];
            rminx = fminf(rminx, vx); rmaxx = fmaxf(rmaxx, vx);
            rminy = fminf(rminy, vy); rmaxy = fmaxf(rmaxy, vy);
        }
        float wr = rmaxx - rminx, hr = rmaxy - rminy;
        bool okl = (wl != 0.0f) && (hl != 0.0f);
        bool okr = (wr != 0.0f) && (hr != 0.0f);
        sc[8]  = okl ? wl : 1.0f;  sc[9]  = okl ? hl : 1.0f;
        sc[10] = okr ? wr : 1.0f;  sc[11] = okr ? hr : 1.0f;
    }
    __syncthreads();
    const float sbx = sc[0], sby = sc[1], sfx = sc[2], sfy = sc[3];
    const float slx = sc[4], sly = sc[5], srx = sc[6], sry = sc[7];
    const float dlx = sc[8], dly = sc[9], drx = sc[10], dry = sc[11];
    for (int k = t; k < 133; k += blockDim.x) {
        float vx = x[2*k], vy = x[2*k + 1];
        if (k < 17) {                 // body
            feat[2*k]   = vx - sbx;  feat[2*k+1] = vy - sby;
        } else if (k < 23) {          // feet
            feat[2*k]   = vx;        feat[2*k+1] = vy;
        } else if (k < 91) {          // face
            feat[2*k]   = vx - sfx;  feat[2*k+1] = vy - sfy;
        } else if (k < 112) {         // left hand + chin2l
            int j = k - 91;
            feat[182 + 2*j] = (vx - slx) / dlx;  feat[183 + 2*j] = (vy - sly) / dly;
            feat[266 + 2*j] = vx - sbx;          feat[267 + 2*j] = vy - sby;
        } else {                      // right hand + chin2r
            int j = k - 112;
            feat[224 + 2*j] = (vx - srx) / drx;  feat[225 + 2*j] = (vy - sry) / dry;
            feat[308 + 2*j] = vx - sbx;          feat[309 + 2*j] = vy - sby;
        }
    }
    __syncthreads();
}

// k1: feat + LSTM layer 0 (h=c=0 => f-gate dead, W_hh unused) + barrier init.
// 256 blocks x 1024 thr. Block b owns hidden units [8b, 8b+8).
// 24 gate-dots (8 units x {i,g,o}) over 16 waves, K=350.
__global__ __launch_bounds__(NTHR) void k1_feat_lstm0(
    const float* __restrict__ x, const float* __restrict__ Wih,
    const float* __restrict__ bih, const float* __restrict__ bhh,
    float* __restrict__ ws)
{
    __shared__ float feat[IN_F];
    __shared__ float gd[8][3];
    compute_feat(x, feat);
    if (blockIdx.x == 0 && threadIdx.x == 0) {
        unsigned* bar = (unsigned*)(ws + 4096);
        bar[0] = 0u; bar[1] = 0u;   // re-arm grid barrier every call
    }
    const int wave = threadIdx.x >> 6, lane = threadIdx.x & 63;
    const int b = blockIdx.x;
    for (int t = wave; t < 24; t += 16) {
        int u = t / 3;
        int gsel = t - u * 3;                       // 0,1,2 -> gates i,g,o
        int gate = (gsel == 0) ? 0 : (gsel == 1 ? 2 : 3);
        int row = gate * HIDDEN + b * 8 + u;
        const float* wr = Wih + (size_t)row * IN_F;
        float acc = 0.0f;
        for (int i = lane; i < IN_F; i += 64) acc += wr[i] * feat[i];
        #pragma unroll
        for (int off = 32; off; off >>= 1) acc += __shfl_down(acc, off);
        if (lane == 0) gd[u][gsel] = acc + bih[row] + bhh[row];
    }
    __syncthreads();
    if (threadIdx.x < 8) {
        int j = b * 8 + threadIdx.x;
        float gi = gd[threadIdx.x][0], gg = gd[threadIdx.x][1], go = gd[threadIdx.x][2];
        float c = sigmoidf_(gi) * tanhf(gg);
        ws[j] = sigmoidf_(go) * tanhf(c);           // h1
    }
}

// k2: LSTM layer 1 (wave-pair per unit, K=2048 split in halves, float4 loads)
//     -> grid barrier -> fc (row per block, strided).
__global__ __launch_bounds__(NTHR) void k2_lstm1_fc(
    const float* __restrict__ Wih, const float* __restrict__ bih,
    const float* __restrict__ bhh, const float* __restrict__ fcw,
    const float* __restrict__ fcb, float* __restrict__ ws,
    float* __restrict__ out)
{
    __shared__ float part[16][3];
    __shared__ float rpart[16];
    const int wave = threadIdx.x >> 6, lane = threadIdx.x & 63;
    const int b = blockIdx.x;
    const float* h1 = ws;
    float* h2 = ws + HIDDEN;

    // ---- layer 1: unit u = b*8 + (wave>>1); K-half = (wave&1)*1024 ----
    {
        const int u = b * 8 + (wave >> 1);
        const int base = (wave & 1) * 1024;
        const float4* h4 = (const float4*)(h1 + base);
        const size_t roff = ((size_t)u * HIDDEN + base) >> 2;   // in float4
        const float4* w0 = (const float4*)Wih + roff;                                    // gate i
        const float4* w1 = (const float4*)Wih + ((size_t)2 * HIDDEN * HIDDEN >> 2) + roff; // gate g
        const float4* w2 = (const float4*)Wih + ((size_t)3 * HIDDEN * HIDDEN >> 2) + roff; // gate o
        float a0 = 0.f, a1 = 0.f, a2 = 0.f;
        #pragma unroll
        for (int it = 0; it < 4; ++it) {
            int idx = it * 64 + lane;
            float4 hv = h4[idx];
            float4 wa = w0[idx], wb = w1[idx], wc = w2[idx];
            a0 += wa.x*hv.x + wa.y*hv.y + wa.z*hv.z + wa.w*hv.w;
            a1 += wb.x*hv.x + wb.y*hv.y + wb.z*hv.z + wb.w*hv.w;
            a2 += wc.x*hv.x + wc.y*hv.y + wc.z*hv.z + wc.w*hv.w;
        }
        #pragma unroll
        for (int off = 32; off; off >>= 1) {
            a0 += __shfl_down(a0, off);
            a1 += __shfl_down(a1, off);
            a2 += __shfl_down(a2, off);
        }
        if (lane == 0) { part[wave][0] = a0; part[wave][1] = a1; part[wave][2] = a2; }
    }
    __syncthreads();
    if (threadIdx.x < 8) {
        int t = threadIdx.x;
        int j = b * 8 + t;
        float gi = part[2*t][0] + part[2*t+1][0] + bih[j]            + bhh[j];
        float gg = part[2*t][1] + part[2*t+1][1] + bih[2*HIDDEN + j] + bhh[2*HIDDEN + j];
        float go = part[2*t][2] + part[2*t+1][2] + bih[3*HIDDEN + j] + bhh[3*HIDDEN + j];
        float c = sigmoidf_(gi) * tanhf(gg);
        h2[j] = sigmoidf_(go) * tanhf(c);
    }
    __syncthreads();

    // ---- grid barrier (256 blocks = 1/CU, guaranteed co-resident) ----
    __threadfence();
    {
        unsigned* cnt  = (unsigned*)(ws + 4096);
        unsigned* flag = cnt + 1;
        if (threadIdx.x == 0) {
            unsigned t = __hip_atomic_fetch_add(cnt, 1u, __ATOMIC_ACQ_REL,
                                                __HIP_MEMORY_SCOPE_AGENT);
            if (t == (unsigned)(gridDim.x - 1)) {
                __hip_atomic_store(flag, 1u, __ATOMIC_RELEASE, __HIP_MEMORY_SCOPE_AGENT);
            } else {
                while (__hip_atomic_load(flag, __ATOMIC_ACQUIRE,
                                         __HIP_MEMORY_SCOPE_AGENT) == 0u) {
                    __builtin_amdgcn_s_sleep(1);
                }
            }
        }
    }
    __syncthreads();

    // ---- fc: out[r] = fc_w[r,:] . h2 + fc_b[r]; rows strided over blocks ----
    const float4* h24 = (const float4*)h2;
    for (int r = b; r < IN_F; r += NBLK) {
        float acc = 0.0f;
        if (threadIdx.x < 512) {                     // 512 float4 = 2048 floats
            float4 w = ((const float4*)(fcw + (size_t)r * HIDDEN))[threadIdx.x];
            float4 v = h24[threadIdx.x];
            acc = w.x*v.x + w.y*v.y + w.z*v.z + w.w*v.w;
        }
        #pragma unroll
        for (int off = 32; off; off >>= 1) acc += __shfl_down(acc, off);
        if (lane == 0) rpart[wave] = acc;
        __syncthreads();
        if (wave == 0) {
            float s = (lane < 16) ? rpart[lane] : 0.0f;
            #pragma unroll
            for (int off = 8; off; off >>= 1) s += __shfl_down(s, off);
            if (lane == 0) out[r] = s + fcb[r];
        }
        __syncthreads();
    }
}

extern "C" void kernel_launch(void* const* d_in, const int* in_sizes, int n_in,
                              void* d_out, int out_size, void* d_ws, size_t ws_size,
                              hipStream_t stream) {
    const float* x     = (const float*)d_in[0];
    const float* W_ih0 = (const float*)d_in[1];
    // d_in[2] = W_hh0 : unused (h0 == 0)
    const float* b_ih0 = (const float*)d_in[3];
    const float* b_hh0 = (const float*)d_in[4];
    const float* W_ih1 = (const float*)d_in[5];
    // d_in[6] = W_hh1 : unused (h == 0 for cell 2 as well)
    const float* b_ih1 = (const float*)d_in[7];
    const float* b_hh1 = (const float*)d_in[8];
    const float* fc_w  = (const float*)d_in[9];
    const float* fc_b  = (const float*)d_in[10];

    float* ws = (float*)d_ws;

    k1_feat_lstm0<<<NBLK, NTHR, 0, stream>>>(x, W_ih0, b_ih0, b_hh0, ws);
    k2_lstm1_fc<<<NBLK, NTHR, 0, stream>>>(W_ih1, b_ih1, b_hh1, fc_w, fc_b,
                                           ws, (float*)d_out);
}

// Round 3
// 27.284 us; speedup vs baseline: 3.4027x; 3.4027x over previous
//
#include <hip/hip_runtime.h>
#include <math.h>

#define HIDDEN 2048
#define IN_F 350

// ws layout (floats): [0 .. 2047] h1.  h2 never leaves K2's LDS.

__device__ __forceinline__ float sigmoidf_(float v) { return 1.0f / (1.0f + expf(-v)); }

// 350-element feature vector from x (133 keypoint pairs) into LDS.
__device__ void compute_feat(const float* __restrict__ x, float* feat) {
    __shared__ float sc[12];
    const int t = threadIdx.x;
    if (t == 0) {
        sc[0] = x[0];   sc[1] = x[1];     // src_body  = kp[0]
        sc[2] = x[106]; sc[3] = x[107];   // src_face  = kp[53]
        sc[4] = x[200]; sc[5] = x[201];   // src_left  = kp[100]
        sc[6] = x[242]; sc[7] = x[243];   // src_right = kp[121]
        float lminx = x[182], lmaxx = x[182], lminy = x[183], lmaxy = x[183];
        for (int j = 1; j < 21; ++j) {
            float vx = x[182 + 2*j], vy = x[183 + 2*j];
            lminx = fminf(lminx, vx); lmaxx = fmaxf(lmaxx, vx);
            lminy = fminf(lminy, vy); lmaxy = fmaxf(lmaxy, vy);
        }
        float wl = lmaxx - lminx, hl = lmaxy - lminy;
        float rminx = x[224], rmaxx = x[224], rminy = x[225], rmaxy = x[225];
        for (int j = 1; j < 21; ++j) {
            float vx = x[224 + 2*j], vy = x[225 + 2*j];
            rminx = fminf(rminx, vx); rmaxx = fmaxf(rmaxx, vx);
            rminy = fminf(rminy, vy); rmaxy = fmaxf(rmaxy, vy);
        }
        float wr = rmaxx - rminx, hr = rmaxy - rminy;
        bool okl = (wl != 0.0f) && (hl != 0.0f);
        bool okr = (wr != 0.0f) && (hr != 0.0f);
        sc[8]  = okl ? wl : 1.0f;  sc[9]  = okl ? hl : 1.0f;
        sc[10] = okr ? wr : 1.0f;  sc[11] = okr ? hr : 1.0f;
    }
    __syncthreads();
    const float sbx = sc[0], sby = sc[1], sfx = sc[2], sfy = sc[3];
    const float slx = sc[4], sly = sc[5], srx = sc[6], sry = sc[7];
    const float dlx = sc[8], dly = sc[9], drx = sc[10], dry = sc[11];
    for (int k = t; k < 133; k += blockDim.x) {
        float vx = x[2*k], vy = x[2*k + 1];
        if (k < 17) {                 // body
            feat[2*k]   = vx - sbx;  feat[2*k+1] = vy - sby;
        } else if (k < 23) {          // feet
            feat[2*k]   = vx;        feat[2*k+1] = vy;
        } else if (k < 91) {          // face
            feat[2*k]   = vx - sfx;  feat[2*k+1] = vy - sfy;
        } else if (k < 112) {         // left hand + chin2l
            int j = k - 91;
            feat[182 + 2*j] = (vx - slx) / dlx;  feat[183 + 2*j] = (vy - sly) / dly;
            feat[266 + 2*j] = vx - sbx;          feat[267 + 2*j] = vy - sby;
        } else {                      // right hand + chin2r
            int j = k - 112;
            feat[224 + 2*j] = (vx - srx) / drx;  feat[225 + 2*j] = (vy - sry) / dry;
            feat[308 + 2*j] = vx - sbx;          feat[309 + 2*j] = vy - sby;
        }
    }
    __syncthreads();
}

// K1: feat + LSTM layer 0 (h=c=0 => f-gate dead, W_hh unused).
// One block (3 waves = gates i,g,o) per hidden unit, K=350.
// Side duty: block j<350 seeds out[j] = fc_b[j] so K2 can atomicAdd into it.
__global__ __launch_bounds__(192) void k1_feat_lstm0(
    const float* __restrict__ x, const float* __restrict__ Wih,
    const float* __restrict__ bih, const float* __restrict__ bhh,
    const float* __restrict__ fcb, float* __restrict__ h1,
    float* __restrict__ out)
{
    __shared__ float feat[IN_F];
    __shared__ float gate_s[3];
    const int j = blockIdx.x;
    if (threadIdx.x == 64 && j < IN_F) out[j] = fcb[j];   // seed bias (stream-ordered before K2)
    compute_feat(x, feat);
    const int wave = threadIdx.x >> 6;
    const int lane = threadIdx.x & 63;
    const int gate = (wave == 0) ? 0 : (wave == 1 ? 2 : 3);   // i, g, o
    const int row = gate * HIDDEN + j;
    const float* wr = Wih + (size_t)row * IN_F;
    float acc = 0.0f;
    for (int i = lane; i < IN_F; i += 64) acc += wr[i] * feat[i];
    #pragma unroll
    for (int off = 32; off; off >>= 1) acc += __shfl_down(acc, off);
    if (lane == 0) gate_s[wave] = acc + bih[row] + bhh[row];
    __syncthreads();
    if (threadIdx.x == 0) {
        float c = sigmoidf_(gate_s[0]) * tanhf(gate_s[1]);
        h1[j] = sigmoidf_(gate_s[2]) * tanhf(c);
    }
}

// K2: LSTM layer 1 (h=c=0 again) + fused partial-fc, NO grid sync.
// 256 blocks x 1024 thr; block b owns hidden units [8b, 8b+8).
// Layer 1: wave-pair per unit, K=2048 split in halves, float4 loads.
// Then: out[r] += fcw[r, 8b..8b+8) . h2_local  via one atomicAdd per (block,row).
__global__ __launch_bounds__(1024) void k2_lstm1_fc(
    const float* __restrict__ Wih, const float* __restrict__ bih,
    const float* __restrict__ bhh, const float* __restrict__ fcw,
    const float* __restrict__ h1, float* __restrict__ out)
{
    __shared__ float part[16][3];
    __shared__ float h2s[8];
    const int wave = threadIdx.x >> 6, lane = threadIdx.x & 63;
    const int b = blockIdx.x;

    // ---- layer 1: unit u = b*8 + (wave>>1); K-half = (wave&1)*1024 ----
    {
        const int u = b * 8 + (wave >> 1);
        const int base = (wave & 1) * 1024;
        const float4* h4 = (const float4*)(h1 + base);
        const size_t roff = ((size_t)u * HIDDEN + base) >> 2;   // in float4
        const float4* w0 = (const float4*)Wih + roff;                                      // gate i
        const float4* w1 = (const float4*)Wih + ((size_t)2 * HIDDEN * HIDDEN >> 2) + roff; // gate g
        const float4* w2 = (const float4*)Wih + ((size_t)3 * HIDDEN * HIDDEN >> 2) + roff; // gate o
        float a0 = 0.f, a1 = 0.f, a2 = 0.f;
        #pragma unroll
        for (int it = 0; it < 4; ++it) {
            int idx = it * 64 + lane;
            float4 hv = h4[idx];
            float4 wa = w0[idx], wb = w1[idx], wc = w2[idx];
            a0 += wa.x*hv.x + wa.y*hv.y + wa.z*hv.z + wa.w*hv.w;
            a1 += wb.x*hv.x + wb.y*hv.y + wb.z*hv.z + wb.w*hv.w;
            a2 += wc.x*hv.x + wc.y*hv.y + wc.z*hv.z + wc.w*hv.w;
        }
        #pragma unroll
        for (int off = 32; off; off >>= 1) {
            a0 += __shfl_down(a0, off);
            a1 += __shfl_down(a1, off);
            a2 += __shfl_down(a2, off);
        }
        if (lane == 0) { part[wave][0] = a0; part[wave][1] = a1; part[wave][2] = a2; }
    }
    __syncthreads();
    if (threadIdx.x < 8) {
        int t = threadIdx.x;
        int j = b * 8 + t;
        float gi = part[2*t][0] + part[2*t+1][0] + bih[j]            + bhh[j];
        float gg = part[2*t][1] + part[2*t+1][1] + bih[2*HIDDEN + j] + bhh[2*HIDDEN + j];
        float go = part[2*t][2] + part[2*t+1][2] + bih[3*HIDDEN + j] + bhh[3*HIDDEN + j];
        float c = sigmoidf_(gi) * tanhf(gg);
        h2s[t] = sigmoidf_(go) * tanhf(c);          // h2 stays in LDS
    }
    __syncthreads();

    // ---- fused partial fc: thread r accumulates this block's 8 columns ----
    const int r = threadIdx.x;
    if (r < IN_F) {
        const float4* wr4 = (const float4*)(fcw + (size_t)r * HIDDEN + b * 8);
        float4 wa = wr4[0], wb = wr4[1];
        float p = wa.x*h2s[0] + wa.y*h2s[1] + wa.z*h2s[2] + wa.w*h2s[3]
                + wb.x*h2s[4] + wb.y*h2s[5] + wb.z*h2s[6] + wb.w*h2s[7];
        atomicAdd(&out[r], p);
    }
}

extern "C" void kernel_launch(void* const* d_in, const int* in_sizes, int n_in,
                              void* d_out, int out_size, void* d_ws, size_t ws_size,
                              hipStream_t stream) {
    const float* x     = (const float*)d_in[0];
    const float* W_ih0 = (const float*)d_in[1];
    // d_in[2] = W_hh0 : unused (h0 == 0)
    const float* b_ih0 = (const float*)d_in[3];
    const float* b_hh0 = (const float*)d_in[4];
    const float* W_ih1 = (const float*)d_in[5];
    // d_in[6] = W_hh1 : unused (h == 0 for cell 2 as well)
    const float* b_ih1 = (const float*)d_in[7];
    const float* b_hh1 = (const float*)d_in[8];
    const float* fc_w  = (const float*)d_in[9];
    const float* fc_b  = (const float*)d_in[10];

    float* h1  = (float*)d_ws;            // 2048 floats
    float* out = (float*)d_out;           // 350 floats

    k1_feat_lstm0<<<HIDDEN, 192, 0, stream>>>(x, W_ih0, b_ih0, b_hh0, fc_b, h1, out);
    k2_lstm1_fc<<<256, 1024, 0, stream>>>(W_ih1, b_ih1, b_hh1, fc_w, h1, out);
}